// Round 6
// baseline (383.603 us; speedup 1.0000x reference)
//
#include <hip/hip_runtime.h>
#include <hip/hip_bf16.h>

// MHA forward, MI355X gfx950. B=2, T=S=2048, E=1024, H=16, HD=64.
// cvt fp32->bf16 -> qkv GEMM (V^T epilogue via LDS transpose, coalesced) ->
// split-s flash (S^T form, P overlays Ks, LDS-transposed partial-O epilogue) ->
// combine partials -> attn_max (LDS-transposed stores) -> out proj.

using bf16 = __bf16;
typedef __attribute__((ext_vector_type(8))) __bf16 bf16x8;
typedef __attribute__((ext_vector_type(4))) __bf16 bf16x4;
typedef __attribute__((ext_vector_type(4))) float f32x4;

constexpr int Bsz = 2, Tq = 2048, Sk = 2048, NH = 16;
constexpr int E_DIM = 1024;
constexpr float LOG2E = 1.44269504f;

using gas1 = const __attribute__((address_space(1))) void;
using las3 = __attribute__((address_space(3))) void;

__device__ __forceinline__ void gload_lds16(const bf16* g, bf16* l) {
  __builtin_amdgcn_global_load_lds((gas1*)g, (las3*)l, 16, 0, 0);
}
__device__ __forceinline__ float fexp2(float x) { return __builtin_amdgcn_exp2f(x); }

// ---------------- fp32 -> bf16 bulk convert ----------------------------------------
struct CvtArgs {
  const float* src[7];
  bf16* dst[7];
  int start[8];
};
__global__ __launch_bounds__(256) void cvt_f32_bf16(CvtArgs a)
{
  int blk = blockIdx.x;
  int t = 0;
#pragma unroll
  for (int i = 1; i < 7; ++i) t += (blk >= a.start[i]);
  size_t off = ((size_t)(blk - a.start[t]) * 256 + threadIdx.x) * 8;
  const float* s = a.src[t];
  float4 v0 = *(const float4*)&s[off];
  float4 v1 = *(const float4*)&s[off + 4];
  bf16x8 o;
  o[0] = (bf16)v0.x; o[1] = (bf16)v0.y; o[2] = (bf16)v0.z; o[3] = (bf16)v0.w;
  o[4] = (bf16)v1.x; o[5] = (bf16)v1.y; o[6] = (bf16)v1.z; o[7] = (bf16)v1.w;
  *(bf16x8*)&a.dst[t][off] = o;
}

// ---------------- qkv GEMM: BK=64; V path -> Vt[b,h,d,s] via LDS transpose ---------
struct GemmBatch {
  const bf16* A[3];
  const bf16* W[3];
  const float* bias[3];
  bf16* C[3];
  float scale[3];
  int transpose[3];
};
__global__ __launch_bounds__(256) void gemm_qkv(GemmBatch gb)
{
  constexpr int K = 1024, N = 1024;
  const int z = blockIdx.z;
  const bf16* __restrict__ A = gb.A[z];
  const bf16* __restrict__ W = gb.W[z];
  const float* __restrict__ bias = gb.bias[z];
  bf16* __restrict__ C = gb.C[z];
  const float scale = gb.scale[z];

  __shared__ bf16 sm[2 * 128 * 64];   // As | Bs ; reused as V^T transpose buffer
  bf16* const As = sm;
  bf16* const Bs = sm + 128 * 64;

  const int tid = threadIdx.x, wave = tid >> 6, lane = tid & 63;
  const int c = lane & 15, q = lane >> 4;
  const int m0 = blockIdx.y * 128, n0 = blockIdx.x * 128;
  const int wr = wave >> 1, wc = wave & 1;
  const int ksub = lane >> 3;
  const int kperm = ((lane & 7) ^ ksub) * 8;
  const int kx = 8 * (c & 7);

  f32x4 acc[4][4] = {};

  for (int kb = 0; kb < K; kb += 64) {
    __syncthreads();
#pragma unroll
    for (int i = 0; i < 4; ++i) {
      int row = wave * 32 + i * 8 + ksub;
      gload_lds16(&A[(size_t)(m0 + row) * K + kb + kperm], &As[(wave * 32 + i * 8) * 64]);
      gload_lds16(&W[(size_t)(n0 + row) * K + kb + kperm], &Bs[(wave * 32 + i * 8) * 64]);
    }
    __syncthreads();

#pragma unroll
    for (int kk = 0; kk < 2; ++kk) {
      bf16x8 af[4], bf[4];
#pragma unroll
      for (int mf = 0; mf < 4; ++mf)
        af[mf] = *(const bf16x8*)&As[(wr * 64 + mf * 16 + c) * 64 + ((kk * 32 + q * 8) ^ kx)];
#pragma unroll
      for (int nf = 0; nf < 4; ++nf)
        bf[nf] = *(const bf16x8*)&Bs[(wc * 64 + nf * 16 + c) * 64 + ((kk * 32 + q * 8) ^ kx)];
#pragma unroll
      for (int mf = 0; mf < 4; ++mf)
#pragma unroll
        for (int nf = 0; nf < 4; ++nf)
          acc[mf][nf] = __builtin_amdgcn_mfma_f32_16x16x32_bf16(af[mf], bf[nf], acc[mf][nf], 0, 0, 0);
    }
  }

  if (gb.transpose[z]) {
    // transpose through LDS: Tv[col 128][t-chunk4 32], chunk4 XOR-swizzled by 2*(col&15)
    __syncthreads();
    bf16* Tv = sm;
#pragma unroll
    for (int nf = 0; nf < 4; ++nf) {
      int colL = wc * 64 + nf * 16 + c;
      float bv = bias[n0 + colL];
      int xw = 2 * (colL & 15);
#pragma unroll
      for (int mf = 0; mf < 4; ++mf) {
        int chunk4 = wr * 16 + mf * 4 + q;
        bf16x4 pk;
#pragma unroll
        for (int r = 0; r < 4; ++r) pk[r] = (bf16)(acc[mf][nf][r] + bv);
        *(bf16x4*)&Tv[colL * 128 + ((chunk4 ^ xw) << 2)] = pk;
      }
    }
    __syncthreads();
    const int bb = m0 >> 11, tbase = m0 & 2047;
#pragma unroll
    for (int p = 0; p < 8; ++p) {
      int colL = p * 16 + (tid >> 4);
      int j = tid & 15;
      bf16x8 v = *(const bf16x8*)&Tv[colL * 128 + (((2 * j) ^ (2 * (colL & 15))) << 2)];
      int colg = n0 + colL;
      int hh = colg >> 6, d = colg & 63;
      *(bf16x8*)&C[(((size_t)bb * NH + hh) * 64 + d) * 2048 + tbase + j * 8] = v;
    }
  } else {
#pragma unroll
    for (int nf = 0; nf < 4; ++nf) {
      int col = n0 + wc * 64 + nf * 16 + c;
      float bv = bias[col];
#pragma unroll
      for (int mf = 0; mf < 4; ++mf)
#pragma unroll
        for (int r = 0; r < 4; ++r) {
          int row = m0 + wr * 64 + mf * 16 + q * 4 + r;
          C[(size_t)row * N + col] = (bf16)((acc[mf][nf][r] + bv) * scale);
        }
    }
  }
}

// ---------------- out projection: 128x64 tiles, BK=64 ------------------------------
__global__ __launch_bounds__(256) void gemm_out(
    const bf16* __restrict__ A, const bf16* __restrict__ W,
    const float* __restrict__ bias, float* __restrict__ C)
{
  constexpr int K = 1024, N = 1024;
  __shared__ bf16 As[128 * 64];
  __shared__ bf16 Bs[64 * 64];
  const int tid = threadIdx.x, wave = tid >> 6, lane = tid & 63;
  const int c = lane & 15, q = lane >> 4;
  const int m0 = blockIdx.y * 128, n0 = blockIdx.x * 64;
  const int wr = wave >> 1, wc = wave & 1;
  const int ksub = lane >> 3;
  const int kperm = ((lane & 7) ^ ksub) * 8;
  const int kx = 8 * (c & 7);

  f32x4 acc[4][2] = {};

  for (int kb = 0; kb < K; kb += 64) {
    __syncthreads();
#pragma unroll
    for (int i = 0; i < 4; ++i) {
      int row = wave * 32 + i * 8 + ksub;
      gload_lds16(&A[(size_t)(m0 + row) * K + kb + kperm], &As[(wave * 32 + i * 8) * 64]);
    }
#pragma unroll
    for (int i = 0; i < 2; ++i) {
      int row = wave * 16 + i * 8 + ksub;
      gload_lds16(&W[(size_t)(n0 + row) * K + kb + kperm], &Bs[(wave * 16 + i * 8) * 64]);
    }
    __syncthreads();

#pragma unroll
    for (int kk = 0; kk < 2; ++kk) {
      bf16x8 af[4], bf[2];
#pragma unroll
      for (int mf = 0; mf < 4; ++mf)
        af[mf] = *(const bf16x8*)&As[(wr * 64 + mf * 16 + c) * 64 + ((kk * 32 + q * 8) ^ kx)];
#pragma unroll
      for (int nf = 0; nf < 2; ++nf)
        bf[nf] = *(const bf16x8*)&Bs[(wc * 32 + nf * 16 + c) * 64 + ((kk * 32 + q * 8) ^ kx)];
#pragma unroll
      for (int mf = 0; mf < 4; ++mf)
#pragma unroll
        for (int nf = 0; nf < 2; ++nf)
          acc[mf][nf] = __builtin_amdgcn_mfma_f32_16x16x32_bf16(af[mf], bf[nf], acc[mf][nf], 0, 0, 0);
    }
  }

#pragma unroll
  for (int nf = 0; nf < 2; ++nf) {
    int col = n0 + wc * 32 + nf * 16 + c;
    float bv = bias[col];
#pragma unroll
    for (int mf = 0; mf < 4; ++mf)
#pragma unroll
      for (int r = 0; r < 4; ++r) {
        int row = m0 + wr * 64 + mf * 16 + q * 4 + r;
        C[(size_t)row * N + col] = acc[mf][nf][r] + bv;
      }
  }
}

// ---------------- Flash, S^T form, split-s, P overlays Ks --------------------------
// grid (T/128=16, H, B*2); z = b*2 + sHalf; each block does 1024 s in 8 stages of 128.
// LDS: Ks 16K + Vts 16K = 32 KB -> 4 blocks/CU at grid 1024.
__global__ __launch_bounds__(256, 4) void flash_ctx(
    const bf16* __restrict__ Qp, const bf16* __restrict__ Kp, const bf16* __restrict__ Vt,
    bf16* __restrict__ oPart, float* __restrict__ sPart)
{
  __shared__ bf16 Ks[128 * 64];       // [s][k] swizzled; P + O^T overlay here
  __shared__ bf16 Vts[64 * 128];      // [d][s] swizzled

  const int tid = threadIdx.x, wave = tid >> 6, lane = tid & 63;
  const int c = lane & 15, q = lane >> 4;
  const int b = blockIdx.z >> 1, half = blockIdx.z & 1;
  const int h = blockIdx.y, t0 = blockIdx.x * 128;
  const int sBase = half * 1024;
  const size_t baseQ = (size_t)b * Tq * E_DIM + h * 64;
  const size_t baseK = (size_t)b * Sk * E_DIM + h * 64;
  const size_t baseV = ((size_t)b * NH + h) * 64 * 2048;
  const int tw[2] = { t0 + wave * 32 + c, t0 + wave * 32 + c + 16 };

  bf16x8 qf[2][2];
#pragma unroll
  for (int tf = 0; tf < 2; ++tf)
#pragma unroll
    for (int kk = 0; kk < 2; ++kk)
      qf[tf][kk] = *(const bf16x8*)&Qp[baseQ + (size_t)tw[tf] * E_DIM + kk * 32 + q * 8];

  f32x4 o_acc[2][4] = {};
  float m2[2] = {-3e38f, -3e38f}, l_st[2] = {0.f, 0.f};

  const int ksub = lane >> 3;
  const int kperm = ((lane & 7) ^ ksub) * 8;
  const int vsub = lane >> 4;
  const int kx = 8 * (c & 7);
  bf16* const Pw = &Ks[wave * 2048];   // per-wave P region (4 KB), [t-local 32][s 64] swizzled

  for (int st = 0; st < 8; ++st) {
    const int s0 = sBase + st * 128;
    __syncthreads();
#pragma unroll
    for (int i = 0; i < 4; ++i) {
      int srow = wave * 32 + i * 8 + ksub;
      gload_lds16(&Kp[baseK + (size_t)(s0 + srow) * E_DIM + kperm], &Ks[(wave * 32 + i * 8) * 64]);
      int drow = wave * 16 + i * 4 + vsub;
      gload_lds16(&Vt[baseV + (size_t)drow * 2048 + s0 + ((lane & 15) ^ (drow & 7)) * 8],
                  &Vts[(wave * 16 + i * 4) * 128]);
    }
    __syncthreads();

    // S^T[128s][32t]
    f32x4 sa[2][8] = {};
#pragma unroll
    for (int kk = 0; kk < 2; ++kk) {
#pragma unroll
      for (int mf = 0; mf < 8; ++mf) {
        bf16x8 af = *(const bf16x8*)&Ks[(mf * 16 + c) * 64 + ((kk * 32 + q * 8) ^ kx)];
#pragma unroll
        for (int tf = 0; tf < 2; ++tf)
          sa[tf][mf] = __builtin_amdgcn_mfma_f32_16x16x32_bf16(af, qf[tf][kk], sa[tf][mf], 0, 0, 0);
      }
    }

    // online softmax stats for the 128-s stage
    float mn2[2], psum[2] = {0.f, 0.f};
#pragma unroll
    for (int tf = 0; tf < 2; ++tf) {
      float tm = -3e38f;
#pragma unroll
      for (int mf = 0; mf < 8; ++mf)
        tm = fmaxf(tm, fmaxf(fmaxf(sa[tf][mf][0], sa[tf][mf][1]),
                             fmaxf(sa[tf][mf][2], sa[tf][mf][3])));
      tm = fmaxf(tm, __shfl_xor(tm, 16));
      tm = fmaxf(tm, __shfl_xor(tm, 32));
      mn2[tf] = fmaxf(m2[tf], tm * LOG2E);
      float alpha = fexp2(m2[tf] - mn2[tf]);
      m2[tf] = mn2[tf];
      l_st[tf] *= alpha;
#pragma unroll
      for (int mf = 0; mf < 4; ++mf)
#pragma unroll
        for (int r = 0; r < 4; ++r) o_acc[tf][mf][r] *= alpha;
    }

    __syncthreads();   // all QK reads of Ks done -> P may overlay Ks

    // two 64-s sub-steps: exp2 -> P (own-wave Ks region) -> PV
#pragma unroll
    for (int sub = 0; sub < 2; ++sub) {
#pragma unroll
      for (int tf = 0; tf < 2; ++tf) {
        int tl = c + 16 * tf;
#pragma unroll
        for (int mf = 0; mf < 4; ++mf) {
          bf16x4 pb;
#pragma unroll
          for (int r = 0; r < 4; ++r) {
            float p = fexp2(__builtin_fmaf(sa[tf][sub * 4 + mf][r], LOG2E, -mn2[tf]));
            psum[tf] += p;
            pb[r] = (bf16)p;
          }
          *(bf16x4*)&Pw[tl * 64 + (((2 * mf + (q >> 1)) ^ (c & 7)) << 3) + ((q & 1) << 2)] = pb;
        }
      }
#pragma unroll
      for (int kk2 = 0; kk2 < 2; ++kk2) {
        bf16x8 af[4], bfr[2];
#pragma unroll
        for (int mf2 = 0; mf2 < 4; ++mf2)
          af[mf2] = *(const bf16x8*)&Vts[(mf2 * 16 + c) * 128 +
                                         ((sub * 64 + kk2 * 32 + q * 8) ^ kx)];
#pragma unroll
        for (int tf = 0; tf < 2; ++tf)
          bfr[tf] = *(const bf16x8*)&Pw[(c + 16 * tf) * 64 + (((kk2 * 4 + q) ^ (c & 7)) << 3)];
#pragma unroll
        for (int tf = 0; tf < 2; ++tf)
#pragma unroll
          for (int mf2 = 0; mf2 < 4; ++mf2)
            o_acc[tf][mf2] = __builtin_amdgcn_mfma_f32_16x16x32_bf16(af[mf2], bfr[tf], o_acc[tf][mf2], 0, 0, 0);
      }
    }

#pragma unroll
    for (int tf = 0; tf < 2; ++tf) {
      float ps = psum[tf];
      ps += __shfl_xor(ps, 16);
      ps += __shfl_xor(ps, 32);
      l_st[tf] += ps;
    }
  }

  // epilogue: partial O^hat = O/l (bf16) via LDS transpose -> coalesced 128B stores
  __syncthreads();
  bf16* Ot = Ks;   // [t 128][d 64], chunk8 XOR-swizzled by t&7
#pragma unroll
  for (int tf = 0; tf < 2; ++tf) {
    float inv = 1.f / l_st[tf];
    int tl = wave * 32 + 16 * tf + c;
#pragma unroll
    for (int mf2 = 0; mf2 < 4; ++mf2) {
      bf16x4 ov;
#pragma unroll
      for (int r = 0; r < 4; ++r) ov[r] = (bf16)(o_acc[tf][mf2][r] * inv);
      *(bf16x4*)&Ot[tl * 64 + (((2 * mf2 + (q >> 1)) ^ (c & 7)) << 3) + ((q & 1) << 2)] = ov;
    }
    if (q == 0)
      sPart[half * 65536 + ((size_t)b * NH + h) * Tq + tw[tf]] = m2[tf] + __log2f(l_st[tf]);
  }
  __syncthreads();
  const size_t oBase = (size_t)half * 4194304;
#pragma unroll
  for (int it = 0; it < 4; ++it) {
    int tl = it * 32 + (tid >> 3);
    int j = tid & 7;
    bf16x8 v = *(const bf16x8*)&Ot[tl * 64 + ((j ^ (tl & 7)) << 3)];
    *(bf16x8*)&oPart[oBase + ((size_t)b * Tq + t0 + tl) * E_DIM + h * 64 + j * 8] = v;
  }
}

// ---------------- combine the two s-half partials ----------------------------------
__global__ __launch_bounds__(256) void combine_ctx(
    const bf16* __restrict__ oPart, const float* __restrict__ sPart,
    bf16* __restrict__ ctx, float* __restrict__ cOut)
{
  int idx = blockIdx.x * 256 + threadIdx.x;   // 524288
  int row = idx >> 7;                          // b*2048 + t
  int e0 = (idx & 127) * 8;
  int bq = row >> 11, t = row & 2047;
  int h = e0 >> 6;
  int sidx = (bq * NH + h) * 2048 + t;
  float s0v = sPart[sidx], s1v = sPart[65536 + sidx];
  float cm = fmaxf(s0v, s1v);
  float w0 = fexp2(s0v - cm), w1 = fexp2(s1v - cm);
  float inv = 1.f / (w0 + w1);
  size_t off = (size_t)row * 1024 + e0;
  bf16x8 a = *(const bf16x8*)&oPart[off];
  bf16x8 bb = *(const bf16x8*)&oPart[4194304 + off];
  bf16x8 o;
#pragma unroll
  for (int i = 0; i < 8; ++i)
    o[i] = (bf16)(((float)a[i] * w0 + (float)bb[i] * w1) * inv);
  *(bf16x8*)&ctx[off] = o;
  if ((e0 & 63) == 0) cOut[sidx] = cm + __log2f(w0 + w1);
}

// ---------------- attn_max: recompute S^T, p = exp2(s*log2e - c_h), LDS-transposed stores
__global__ __launch_bounds__(256) void attn_max_k(
    const bf16* __restrict__ Qp, const bf16* __restrict__ Kp,
    const float* __restrict__ cArr, float* __restrict__ amax)
{
  __shared__ bf16 Ks[128 * 64];
  const int tid = threadIdx.x, wave = tid >> 6, lane = tid & 63;
  const int c = lane & 15, q = lane >> 4;
  const int b = blockIdx.z, t0 = blockIdx.y * 128, s0 = blockIdx.x * 128;
  const int tw[2] = { t0 + wave * 32 + c, t0 + wave * 32 + c + 16 };
  const int ksub = lane >> 3;
  const int kperm = ((lane & 7) ^ ksub) * 8;
  const int kx = 8 * (c & 7);

  f32x4 vmax[2][8] = {};

  for (int h = 0; h < NH; ++h) {
    const size_t baseK = (size_t)b * Sk * E_DIM + h * 64;
    const size_t baseQ = (size_t)b * Tq * E_DIM + h * 64;
    __syncthreads();
#pragma unroll
    for (int i = 0; i < 4; ++i) {
      int srow = wave * 32 + i * 8 + ksub;
      gload_lds16(&Kp[baseK + (size_t)(s0 + srow) * E_DIM + kperm], &Ks[(wave * 32 + i * 8) * 64]);
    }
    bf16x8 qf[2][2];
    float ch[2];
#pragma unroll
    for (int tf = 0; tf < 2; ++tf) {
#pragma unroll
      for (int kk = 0; kk < 2; ++kk)
        qf[tf][kk] = *(const bf16x8*)&Qp[baseQ + (size_t)tw[tf] * E_DIM + kk * 32 + q * 8];
      ch[tf] = cArr[((size_t)b * NH + h) * Tq + tw[tf]];
    }
    __syncthreads();

#pragma unroll
    for (int mf = 0; mf < 8; ++mf) {
      f32x4 sa[2] = {};
#pragma unroll
      for (int kk = 0; kk < 2; ++kk) {
        bf16x8 af = *(const bf16x8*)&Ks[(mf * 16 + c) * 64 + ((kk * 32 + q * 8) ^ kx)];
#pragma unroll
        for (int tf = 0; tf < 2; ++tf)
          sa[tf] = __builtin_amdgcn_mfma_f32_16x16x32_bf16(af, qf[tf][kk], sa[tf], 0, 0, 0);
      }
#pragma unroll
      for (int tf = 0; tf < 2; ++tf)
#pragma unroll
        for (int r = 0; r < 4; ++r) {
          float p = fexp2(__builtin_fmaf(sa[tf][r], LOG2E, -ch[tf]));
          vmax[tf][mf][r] = fmaxf(vmax[tf][mf][r], p);
        }
    }
  }

  // LDS-transposed stores: Tf[t 128][s-local 32] fp32, 4 passes of 32 s
  __syncthreads();
  float* Tf = (float*)Ks;   // 16 KB = 128*32 floats
#pragma unroll
  for (int pp = 0; pp < 4; ++pp) {
#pragma unroll
    for (int tf = 0; tf < 2; ++tf) {
      int tl = wave * 32 + 16 * tf + c;
#pragma unroll
      for (int ml = 0; ml < 2; ++ml) {
        int chunk4 = ml * 4 + q;
        *(f32x4*)&Tf[tl * 32 + ((chunk4 ^ (c & 7)) << 2)] = vmax[tf][2 * pp + ml];
      }
    }
    __syncthreads();
#pragma unroll
    for (int it = 0; it < 4; ++it) {
      int trow = it * 32 + (tid >> 3);
      int j = tid & 7;
      f32x4 v = *(const f32x4*)&Tf[trow * 32 + ((j ^ (trow & 7)) << 2)];
      *(f32x4*)&amax[((size_t)b * Tq + t0 + trow) * Sk + s0 + pp * 32 + j * 4] = v;
    }
    __syncthreads();
  }
}

// ---------------- launch -----------------------------------------------------------
extern "C" void kernel_launch(void* const* d_in, const int* in_sizes, int n_in,
                              void* d_out, int out_size, void* d_ws, size_t ws_size,
                              hipStream_t stream)
{
  const float* query = (const float*)d_in[0];
  const float* key_i = (const float*)d_in[1];
  const float* value = (const float*)d_in[2];
  const float* Wq = (const float*)d_in[5];
  const float* bq = (const float*)d_in[6];
  const float* Wk = (const float*)d_in[7];
  const float* bk = (const float*)d_in[8];
  const float* Wv = (const float*)d_in[9];
  const float* bv = (const float*)d_in[10];
  const float* Wo = (const float*)d_in[11];
  const float* bo = (const float*)d_in[12];

  float* outp = (float*)d_out;
  float* amax = outp + (size_t)Bsz * Tq * E_DIM;

  char* ws = (char*)d_ws;
  bf16* Xq    = (bf16*)(ws);                 // 8 MiB; reused as ctx after combine
  bf16* Xk    = (bf16*)(ws + 8388608);
  bf16* Xv    = (bf16*)(ws + 16777216);
  bf16* oPart = (bf16*)(ws + 8388608);       // overlays Xk+Xv (dead after qkv), 16 MiB
  bf16* Wqb = (bf16*)(ws + 25165824);
  bf16* Wkb = (bf16*)(ws + 27262976);
  bf16* Wvb = (bf16*)(ws + 29360128);
  bf16* Wob = (bf16*)(ws + 31457280);
  bf16* Qp  = (bf16*)(ws + 33554432);
  bf16* Kp  = (bf16*)(ws + 41943040);
  bf16* Vt  = (bf16*)(ws + 50331648);
  bf16* ctx = Xq;
  float* sPart = (float*)(ws + 58720256);    // 512 KiB (2 halves)
  float* cA    = (float*)(ws + 59244544);    // 256 KiB

  CvtArgs ca;
  ca.src[0] = query; ca.dst[0] = Xq;
  ca.src[1] = key_i; ca.dst[1] = Xk;
  ca.src[2] = value; ca.dst[2] = Xv;
  ca.src[3] = Wq;    ca.dst[3] = Wqb;
  ca.src[4] = Wk;    ca.dst[4] = Wkb;
  ca.src[5] = Wv;    ca.dst[5] = Wvb;
  ca.src[6] = Wo;    ca.dst[6] = Wob;
  ca.start[0] = 0;    ca.start[1] = 2048; ca.start[2] = 4096; ca.start[3] = 6144;
  ca.start[4] = 6656; ca.start[5] = 7168; ca.start[6] = 7680; ca.start[7] = 8192;
  cvt_f32_bf16<<<8192, 256, 0, stream>>>(ca);

  GemmBatch g1;
  g1.A[0] = Xq; g1.A[1] = Xk; g1.A[2] = Xv;
  g1.W[0] = Wqb; g1.W[1] = Wkb; g1.W[2] = Wvb;
  g1.bias[0] = bq; g1.bias[1] = bk; g1.bias[2] = bv;
  g1.C[0] = Qp; g1.C[1] = Kp; g1.C[2] = Vt;
  g1.scale[0] = 0.125f; g1.scale[1] = 1.f; g1.scale[2] = 1.f;
  g1.transpose[0] = 0; g1.transpose[1] = 0; g1.transpose[2] = 1;
  gemm_qkv<<<dim3(8, 32, 3), 256, 0, stream>>>(g1);

  flash_ctx<<<dim3(16, 16, 4), 256, 0, stream>>>(Qp, Kp, Vt, oPart, sPart);
  combine_ctx<<<2048, 256, 0, stream>>>(oPart, sPart, ctx, cA);
  attn_max_k<<<dim3(16, 16, 2), 256, 0, stream>>>(Qp, Kp, cA, amax);
  gemm_out<<<dim3(16, 32), 256, 0, stream>>>(ctx, Wob, bo, outp);
}

// Round 7
// 302.670 us; speedup vs baseline: 1.2674x; 1.2674x over previous
//
#include <hip/hip_runtime.h>
#include <hip/hip_bf16.h>

// MHA forward, MI355X gfx950. B=2, T=S=2048, E=1024, H=16, HD=64.
// cvt fp32->bf16 -> qkv GEMM BK=64 (V^T epilogue via LDS transpose) ->
// S^T flash (s-stage 128, exp2 softmax, per-wave P hop; blockIdx.x=h for XCD-local K/V) ->
// attn_max (c=m*log2e+log2 l, LDS-transposed coalesced stores) -> out proj.

using bf16 = __bf16;
typedef __attribute__((ext_vector_type(8))) __bf16 bf16x8;
typedef __attribute__((ext_vector_type(4))) __bf16 bf16x4;
typedef __attribute__((ext_vector_type(4))) float f32x4;

constexpr int Bsz = 2, Tq = 2048, Sk = 2048, NH = 16;
constexpr int E_DIM = 1024;
constexpr float LOG2E = 1.44269504f;

using gas1 = const __attribute__((address_space(1))) void;
using las3 = __attribute__((address_space(3))) void;

__device__ __forceinline__ void gload_lds16(const bf16* g, bf16* l) {
  __builtin_amdgcn_global_load_lds((gas1*)g, (las3*)l, 16, 0, 0);
}
__device__ __forceinline__ float fexp2(float x) { return __builtin_amdgcn_exp2f(x); }

// ---------------- fp32 -> bf16 bulk convert ----------------------------------------
struct CvtArgs {
  const float* src[7];
  bf16* dst[7];
  int start[8];
};
__global__ __launch_bounds__(256) void cvt_f32_bf16(CvtArgs a)
{
  int blk = blockIdx.x;
  int t = 0;
#pragma unroll
  for (int i = 1; i < 7; ++i) t += (blk >= a.start[i]);
  size_t off = ((size_t)(blk - a.start[t]) * 256 + threadIdx.x) * 8;
  const float* s = a.src[t];
  float4 v0 = *(const float4*)&s[off];
  float4 v1 = *(const float4*)&s[off + 4];
  bf16x8 o;
  o[0] = (bf16)v0.x; o[1] = (bf16)v0.y; o[2] = (bf16)v0.z; o[3] = (bf16)v0.w;
  o[4] = (bf16)v1.x; o[5] = (bf16)v1.y; o[6] = (bf16)v1.z; o[7] = (bf16)v1.w;
  *(bf16x8*)&a.dst[t][off] = o;
}

// ---------------- qkv GEMM: BK=64; V path -> Vt[b,h,d,s] via LDS transpose ---------
struct GemmBatch {
  const bf16* A[3];
  const bf16* W[3];
  const float* bias[3];
  bf16* C[3];
  float scale[3];
  int transpose[3];
};
__global__ __launch_bounds__(256) void gemm_qkv(GemmBatch gb)
{
  constexpr int K = 1024, N = 1024;
  const int z = blockIdx.z;
  const bf16* __restrict__ A = gb.A[z];
  const bf16* __restrict__ W = gb.W[z];
  const float* __restrict__ bias = gb.bias[z];
  bf16* __restrict__ C = gb.C[z];
  const float scale = gb.scale[z];

  __shared__ bf16 sm[2 * 128 * 64];   // As | Bs ; reused as V^T transpose buffer
  bf16* const As = sm;
  bf16* const Bs = sm + 128 * 64;

  const int tid = threadIdx.x, wave = tid >> 6, lane = tid & 63;
  const int c = lane & 15, q = lane >> 4;
  const int m0 = blockIdx.y * 128, n0 = blockIdx.x * 128;
  const int wr = wave >> 1, wc = wave & 1;
  const int ksub = lane >> 3;
  const int kperm = ((lane & 7) ^ ksub) * 8;
  const int kx = 8 * (c & 7);

  f32x4 acc[4][4] = {};

  for (int kb = 0; kb < K; kb += 64) {
    __syncthreads();
#pragma unroll
    for (int i = 0; i < 4; ++i) {
      int row = wave * 32 + i * 8 + ksub;
      gload_lds16(&A[(size_t)(m0 + row) * K + kb + kperm], &As[(wave * 32 + i * 8) * 64]);
      gload_lds16(&W[(size_t)(n0 + row) * K + kb + kperm], &Bs[(wave * 32 + i * 8) * 64]);
    }
    __syncthreads();

#pragma unroll
    for (int kk = 0; kk < 2; ++kk) {
      bf16x8 af[4], bf[4];
#pragma unroll
      for (int mf = 0; mf < 4; ++mf)
        af[mf] = *(const bf16x8*)&As[(wr * 64 + mf * 16 + c) * 64 + ((kk * 32 + q * 8) ^ kx)];
#pragma unroll
      for (int nf = 0; nf < 4; ++nf)
        bf[nf] = *(const bf16x8*)&Bs[(wc * 64 + nf * 16 + c) * 64 + ((kk * 32 + q * 8) ^ kx)];
#pragma unroll
      for (int mf = 0; mf < 4; ++mf)
#pragma unroll
        for (int nf = 0; nf < 4; ++nf)
          acc[mf][nf] = __builtin_amdgcn_mfma_f32_16x16x32_bf16(af[mf], bf[nf], acc[mf][nf], 0, 0, 0);
    }
  }

  if (gb.transpose[z]) {
    __syncthreads();
    bf16* Tv = sm;
#pragma unroll
    for (int nf = 0; nf < 4; ++nf) {
      int colL = wc * 64 + nf * 16 + c;
      float bv = bias[n0 + colL];
      int xw = 2 * (colL & 15);
#pragma unroll
      for (int mf = 0; mf < 4; ++mf) {
        int chunk4 = wr * 16 + mf * 4 + q;
        bf16x4 pk;
#pragma unroll
        for (int r = 0; r < 4; ++r) pk[r] = (bf16)(acc[mf][nf][r] + bv);
        *(bf16x4*)&Tv[colL * 128 + ((chunk4 ^ xw) << 2)] = pk;
      }
    }
    __syncthreads();
    const int bb = m0 >> 11, tbase = m0 & 2047;
#pragma unroll
    for (int p = 0; p < 8; ++p) {
      int colL = p * 16 + (tid >> 4);
      int j = tid & 15;
      bf16x8 v = *(const bf16x8*)&Tv[colL * 128 + (((2 * j) ^ (2 * (colL & 15))) << 2)];
      int colg = n0 + colL;
      int hh = colg >> 6, d = colg & 63;
      *(bf16x8*)&C[(((size_t)bb * NH + hh) * 64 + d) * 2048 + tbase + j * 8] = v;
    }
  } else {
#pragma unroll
    for (int nf = 0; nf < 4; ++nf) {
      int col = n0 + wc * 64 + nf * 16 + c;
      float bv = bias[col];
#pragma unroll
      for (int mf = 0; mf < 4; ++mf)
#pragma unroll
        for (int r = 0; r < 4; ++r) {
          int row = m0 + wr * 64 + mf * 16 + q * 4 + r;
          C[(size_t)row * N + col] = (bf16)((acc[mf][nf][r] + bv) * scale);
        }
    }
  }
}

// ---------------- out projection: 128x64 tiles, BK=64 ------------------------------
__global__ __launch_bounds__(256) void gemm_out(
    const bf16* __restrict__ A, const bf16* __restrict__ W,
    const float* __restrict__ bias, float* __restrict__ C)
{
  constexpr int K = 1024, N = 1024;
  __shared__ bf16 As[128 * 64];
  __shared__ bf16 Bs[64 * 64];
  const int tid = threadIdx.x, wave = tid >> 6, lane = tid & 63;
  const int c = lane & 15, q = lane >> 4;
  const int m0 = blockIdx.y * 128, n0 = blockIdx.x * 64;
  const int wr = wave >> 1, wc = wave & 1;
  const int ksub = lane >> 3;
  const int kperm = ((lane & 7) ^ ksub) * 8;
  const int kx = 8 * (c & 7);

  f32x4 acc[4][2] = {};

  for (int kb = 0; kb < K; kb += 64) {
    __syncthreads();
#pragma unroll
    for (int i = 0; i < 4; ++i) {
      int row = wave * 32 + i * 8 + ksub;
      gload_lds16(&A[(size_t)(m0 + row) * K + kb + kperm], &As[(wave * 32 + i * 8) * 64]);
    }
#pragma unroll
    for (int i = 0; i < 2; ++i) {
      int row = wave * 16 + i * 8 + ksub;
      gload_lds16(&W[(size_t)(n0 + row) * K + kb + kperm], &Bs[(wave * 16 + i * 8) * 64]);
    }
    __syncthreads();

#pragma unroll
    for (int kk = 0; kk < 2; ++kk) {
      bf16x8 af[4], bf[2];
#pragma unroll
      for (int mf = 0; mf < 4; ++mf)
        af[mf] = *(const bf16x8*)&As[(wr * 64 + mf * 16 + c) * 64 + ((kk * 32 + q * 8) ^ kx)];
#pragma unroll
      for (int nf = 0; nf < 2; ++nf)
        bf[nf] = *(const bf16x8*)&Bs[(wc * 32 + nf * 16 + c) * 64 + ((kk * 32 + q * 8) ^ kx)];
#pragma unroll
      for (int mf = 0; mf < 4; ++mf)
#pragma unroll
        for (int nf = 0; nf < 2; ++nf)
          acc[mf][nf] = __builtin_amdgcn_mfma_f32_16x16x32_bf16(af[mf], bf[nf], acc[mf][nf], 0, 0, 0);
    }
  }

#pragma unroll
  for (int nf = 0; nf < 2; ++nf) {
    int col = n0 + wc * 32 + nf * 16 + c;
    float bv = bias[col];
#pragma unroll
    for (int mf = 0; mf < 4; ++mf)
#pragma unroll
      for (int r = 0; r < 4; ++r) {
        int row = m0 + wr * 64 + mf * 16 + q * 4 + r;
        C[(size_t)row * N + col] = acc[mf][nf][r] + bv;
      }
  }
}

// ---------------- Flash, S^T form, s-stage 128, exp2 softmax -----------------------
// grid (H=16, T/128=16, B); blockIdx.x = h so all 16 t-blocks of a head share an XCD
// (linear id mod 8 == h mod 8) -> K/V L2-local. Wave owns 32 t.
__global__ __launch_bounds__(256, 2) void flash_ctx(
    const bf16* __restrict__ Qp, const bf16* __restrict__ Kp, const bf16* __restrict__ Vt,
    bf16* __restrict__ ctx, float* __restrict__ cOut)
{
  __shared__ bf16 Ks[128 * 64];       // [s][k], chunk ^ (s&7)
  __shared__ bf16 Vts[64 * 128];      // [d][s], chunk swizzled
  __shared__ bf16 Ps[4][32 * 68];     // per-wave P [t-local][64s sub-tile], pad 68

  const int tid = threadIdx.x, wave = tid >> 6, lane = tid & 63;
  const int c = lane & 15, q = lane >> 4;
  const int b = blockIdx.z, h = blockIdx.x, t0 = blockIdx.y * 128;
  const size_t baseQ = (size_t)b * Tq * E_DIM + h * 64;
  const size_t baseK = (size_t)b * Sk * E_DIM + h * 64;
  const size_t baseV = ((size_t)b * NH + h) * 64 * 2048;
  const int tw[2] = { t0 + wave * 32 + c, t0 + wave * 32 + c + 16 };

  bf16x8 qf[2][2];
#pragma unroll
  for (int tf = 0; tf < 2; ++tf)
#pragma unroll
    for (int kk = 0; kk < 2; ++kk)
      qf[tf][kk] = *(const bf16x8*)&Qp[baseQ + (size_t)tw[tf] * E_DIM + kk * 32 + q * 8];

  f32x4 o_acc[2][4] = {};
  float m2[2] = {-3e38f, -3e38f}, l_st[2] = {0.f, 0.f};

  const int ksub = lane >> 3;
  const int kperm = ((lane & 7) ^ ksub) * 8;
  const int vsub = lane >> 4;
  const int kx = 8 * (c & 7);

  for (int s0 = 0; s0 < Sk; s0 += 128) {
    __syncthreads();
#pragma unroll
    for (int i = 0; i < 4; ++i) {
      int srow = wave * 32 + i * 8 + ksub;
      gload_lds16(&Kp[baseK + (size_t)(s0 + srow) * E_DIM + kperm], &Ks[(wave * 32 + i * 8) * 64]);
      int drow = wave * 16 + i * 4 + vsub;
      int vsw = (4 * (i & 1) + vsub);
      gload_lds16(&Vt[baseV + (size_t)drow * 2048 + s0 + (((lane & 15) ^ vsw) * 8)],
                  &Vts[(wave * 16 + i * 4) * 128]);
    }
    __syncthreads();

    // S^T[128s][32t]
    f32x4 sa[2][8] = {};
#pragma unroll
    for (int kk = 0; kk < 2; ++kk) {
#pragma unroll
      for (int mf = 0; mf < 8; ++mf) {
        bf16x8 af = *(const bf16x8*)&Ks[(mf * 16 + c) * 64 + ((kk * 32 + q * 8) ^ kx)];
#pragma unroll
        for (int tf = 0; tf < 2; ++tf)
          sa[tf][mf] = __builtin_amdgcn_mfma_f32_16x16x32_bf16(af, qf[tf][kk], sa[tf][mf], 0, 0, 0);
      }
    }

    // online softmax over full 128-s stage
    float mn2[2], psum[2] = {0.f, 0.f};
#pragma unroll
    for (int tf = 0; tf < 2; ++tf) {
      float tm = -3e38f;
#pragma unroll
      for (int mf = 0; mf < 8; ++mf)
        tm = fmaxf(tm, fmaxf(fmaxf(sa[tf][mf][0], sa[tf][mf][1]),
                             fmaxf(sa[tf][mf][2], sa[tf][mf][3])));
      tm = fmaxf(tm, __shfl_xor(tm, 16));
      tm = fmaxf(tm, __shfl_xor(tm, 32));
      mn2[tf] = fmaxf(m2[tf], tm * LOG2E);
      float alpha = fexp2(m2[tf] - mn2[tf]);
      m2[tf] = mn2[tf];
      l_st[tf] *= alpha;
#pragma unroll
      for (int mf = 0; mf < 4; ++mf)
#pragma unroll
        for (int r = 0; r < 4; ++r) o_acc[tf][mf][r] *= alpha;
    }

    // two 64-s sub-steps: exp2 -> per-wave P -> PV
#pragma unroll
    for (int sub = 0; sub < 2; ++sub) {
#pragma unroll
      for (int tf = 0; tf < 2; ++tf)
#pragma unroll
        for (int mf = 0; mf < 4; ++mf) {
          bf16x4 pb;
#pragma unroll
          for (int r = 0; r < 4; ++r) {
            float p = fexp2(__builtin_fmaf(sa[tf][sub * 4 + mf][r], LOG2E, -mn2[tf]));
            psum[tf] += p;
            pb[r] = (bf16)p;
          }
          *(bf16x4*)&Ps[wave][(c + 16 * tf) * 68 + mf * 16 + q * 4] = pb;
        }
#pragma unroll
      for (int kk2 = 0; kk2 < 2; ++kk2) {
        bf16x8 af[4], bfr[2];
#pragma unroll
        for (int mf2 = 0; mf2 < 4; ++mf2)
          af[mf2] = *(const bf16x8*)&Vts[(mf2 * 16 + c) * 128 +
                                         ((sub * 64 + kk2 * 32 + q * 8) ^ kx)];
#pragma unroll
        for (int tf = 0; tf < 2; ++tf)
          bfr[tf] = *(const bf16x8*)&Ps[wave][(c + 16 * tf) * 68 + kk2 * 32 + q * 8];
#pragma unroll
        for (int tf = 0; tf < 2; ++tf)
#pragma unroll
          for (int mf2 = 0; mf2 < 4; ++mf2)
            o_acc[tf][mf2] = __builtin_amdgcn_mfma_f32_16x16x32_bf16(af[mf2], bfr[tf], o_acc[tf][mf2], 0, 0, 0);
      }
    }

#pragma unroll
    for (int tf = 0; tf < 2; ++tf) {
      float ps = psum[tf];
      ps += __shfl_xor(ps, 16);
      ps += __shfl_xor(ps, 32);
      l_st[tf] += ps;
    }
  }

  // epilogue: ctx = O/l; c = m2 + log2(l) for attn_max
#pragma unroll
  for (int tf = 0; tf < 2; ++tf) {
    float inv = 1.f / l_st[tf];
#pragma unroll
    for (int mf2 = 0; mf2 < 4; ++mf2) {
      bf16x4 ov;
#pragma unroll
      for (int r = 0; r < 4; ++r) ov[r] = (bf16)(o_acc[tf][mf2][r] * inv);
      *(bf16x4*)&ctx[baseQ + (size_t)tw[tf] * E_DIM + mf2 * 16 + q * 4] = ov;
    }
    if (q == 0)
      cOut[((size_t)b * NH + h) * Tq + tw[tf]] = m2[tf] + __log2f(l_st[tf]);
  }
}

// ---------------- attn_max: recompute S^T, p = exp2(s*log2e - c_h) -----------------
// grid (S/128=16, T/128=16, B); x = s-block -> s-sharers XCD-local already.
__global__ __launch_bounds__(256) void attn_max_k(
    const bf16* __restrict__ Qp, const bf16* __restrict__ Kp,
    const float* __restrict__ cArr, float* __restrict__ amax)
{
  __shared__ bf16 Ks[128 * 64];
  const int tid = threadIdx.x, wave = tid >> 6, lane = tid & 63;
  const int c = lane & 15, q = lane >> 4;
  const int b = blockIdx.z, t0 = blockIdx.y * 128, s0 = blockIdx.x * 128;
  const int tw[2] = { t0 + wave * 32 + c, t0 + wave * 32 + c + 16 };
  const int ksub = lane >> 3;
  const int kperm = ((lane & 7) ^ ksub) * 8;
  const int kx = 8 * (c & 7);

  f32x4 vmax[2][8] = {};

  for (int h = 0; h < NH; ++h) {
    const size_t baseK = (size_t)b * Sk * E_DIM + h * 64;
    const size_t baseQ = (size_t)b * Tq * E_DIM + h * 64;
    __syncthreads();
#pragma unroll
    for (int i = 0; i < 4; ++i) {
      int srow = wave * 32 + i * 8 + ksub;
      gload_lds16(&Kp[baseK + (size_t)(s0 + srow) * E_DIM + kperm], &Ks[(wave * 32 + i * 8) * 64]);
    }
    bf16x8 qf[2][2];
    float ch[2];
#pragma unroll
    for (int tf = 0; tf < 2; ++tf) {
#pragma unroll
      for (int kk = 0; kk < 2; ++kk)
        qf[tf][kk] = *(const bf16x8*)&Qp[baseQ + (size_t)tw[tf] * E_DIM + kk * 32 + q * 8];
      ch[tf] = cArr[((size_t)b * NH + h) * Tq + tw[tf]];
    }
    __syncthreads();

#pragma unroll
    for (int mf = 0; mf < 8; ++mf) {
      f32x4 sa[2] = {};
#pragma unroll
      for (int kk = 0; kk < 2; ++kk) {
        bf16x8 af = *(const bf16x8*)&Ks[(mf * 16 + c) * 64 + ((kk * 32 + q * 8) ^ kx)];
#pragma unroll
        for (int tf = 0; tf < 2; ++tf)
          sa[tf] = __builtin_amdgcn_mfma_f32_16x16x32_bf16(af, qf[tf][kk], sa[tf], 0, 0, 0);
      }
#pragma unroll
      for (int tf = 0; tf < 2; ++tf)
#pragma unroll
        for (int r = 0; r < 4; ++r) {
          float p = fexp2(__builtin_fmaf(sa[tf][r], LOG2E, -ch[tf]));
          vmax[tf][mf][r] = fmaxf(vmax[tf][mf][r], p);
        }
    }
  }

  // LDS-transposed coalesced stores: Tf[t 128][s-local 32] fp32, 4 passes
  __syncthreads();
  float* Tf = (float*)Ks;
#pragma unroll
  for (int pp = 0; pp < 4; ++pp) {
#pragma unroll
    for (int tf = 0; tf < 2; ++tf) {
      int tl = wave * 32 + 16 * tf + c;
#pragma unroll
      for (int ml = 0; ml < 2; ++ml) {
        int chunk4 = ml * 4 + q;
        *(f32x4*)&Tf[tl * 32 + ((chunk4 ^ (c & 7)) << 2)] = vmax[tf][2 * pp + ml];
      }
    }
    __syncthreads();
#pragma unroll
    for (int it = 0; it < 4; ++it) {
      int trow = it * 32 + (tid >> 3);
      int j = tid & 7;
      f32x4 v = *(const f32x4*)&Tf[trow * 32 + ((j ^ (trow & 7)) << 2)];
      *(f32x4*)&amax[((size_t)b * Tq + t0 + trow) * Sk + s0 + pp * 32 + j * 4] = v;
    }
    __syncthreads();
  }
}

// ---------------- launch -----------------------------------------------------------
extern "C" void kernel_launch(void* const* d_in, const int* in_sizes, int n_in,
                              void* d_out, int out_size, void* d_ws, size_t ws_size,
                              hipStream_t stream)
{
  const float* query = (const float*)d_in[0];
  const float* key_i = (const float*)d_in[1];
  const float* value = (const float*)d_in[2];
  const float* Wq = (const float*)d_in[5];
  const float* bq = (const float*)d_in[6];
  const float* Wk = (const float*)d_in[7];
  const float* bk = (const float*)d_in[8];
  const float* Wv = (const float*)d_in[9];
  const float* bv = (const float*)d_in[10];
  const float* Wo = (const float*)d_in[11];
  const float* bo = (const float*)d_in[12];

  float* outp = (float*)d_out;
  float* amax = outp + (size_t)Bsz * Tq * E_DIM;

  char* ws = (char*)d_ws;
  bf16* Xq  = (bf16*)(ws);
  bf16* Xk  = (bf16*)(ws + 8388608);
  bf16* Xv  = (bf16*)(ws + 16777216);
  bf16* Wqb = (bf16*)(ws + 25165824);
  bf16* Wkb = (bf16*)(ws + 27262976);
  bf16* Wvb = (bf16*)(ws + 29360128);
  bf16* Wob = (bf16*)(ws + 31457280);
  bf16* Qp  = (bf16*)(ws + 33554432);
  bf16* Kp  = (bf16*)(ws + 41943040);
  bf16* Vt  = (bf16*)(ws + 50331648);
  bf16* ctx = Xq;  // Xq dead after qkv GEMM
  float* cA = (float*)(ws + 58720256);

  CvtArgs ca;
  ca.src[0] = query; ca.dst[0] = Xq;
  ca.src[1] = key_i; ca.dst[1] = Xk;
  ca.src[2] = value; ca.dst[2] = Xv;
  ca.src[3] = Wq;    ca.dst[3] = Wqb;
  ca.src[4] = Wk;    ca.dst[4] = Wkb;
  ca.src[5] = Wv;    ca.dst[5] = Wvb;
  ca.src[6] = Wo;    ca.dst[6] = Wob;
  ca.start[0] = 0;    ca.start[1] = 2048; ca.start[2] = 4096; ca.start[3] = 6144;
  ca.start[4] = 6656; ca.start[5] = 7168; ca.start[6] = 7680; ca.start[7] = 8192;
  cvt_f32_bf16<<<8192, 256, 0, stream>>>(ca);

  GemmBatch g1;
  g1.A[0] = Xq; g1.A[1] = Xk; g1.A[2] = Xv;
  g1.W[0] = Wqb; g1.W[1] = Wkb; g1.W[2] = Wvb;
  g1.bias[0] = bq; g1.bias[1] = bk; g1.bias[2] = bv;
  g1.C[0] = Qp; g1.C[1] = Kp; g1.C[2] = Vt;
  g1.scale[0] = 0.125f; g1.scale[1] = 1.f; g1.scale[2] = 1.f;
  g1.transpose[0] = 0; g1.transpose[1] = 0; g1.transpose[2] = 1;
  gemm_qkv<<<dim3(8, 32, 3), 256, 0, stream>>>(g1);

  flash_ctx<<<dim3(16, 16, 2), 256, 0, stream>>>(Qp, Kp, Vt, ctx, cA);
  attn_max_k<<<dim3(16, 16, 2), 256, 0, stream>>>(Qp, Kp, cA, amax);
  gemm_out<<<dim3(16, 32), 256, 0, stream>>>(ctx, Wob, bo, outp);
}

// Round 8
// 293.469 us; speedup vs baseline: 1.3071x; 1.0314x over previous
//
#include <hip/hip_runtime.h>
#include <hip/hip_bf16.h>

// MHA forward, MI355X gfx950. B=2, T=S=2048, E=1024, H=16, HD=64.
// cvt fp32->bf16 -> qkv GEMM BK=64 (m-block on x for XCD-local A; V^T epilogue via LDS) ->
// S^T flash (blockIdx.x=h for XCD-local K/V) -> attn_max (double-buffered K DMA) ->
// out proj (m-block on x).

using bf16 = __bf16;
typedef __attribute__((ext_vector_type(8))) __bf16 bf16x8;
typedef __attribute__((ext_vector_type(4))) __bf16 bf16x4;
typedef __attribute__((ext_vector_type(4))) float f32x4;

constexpr int Bsz = 2, Tq = 2048, Sk = 2048, NH = 16;
constexpr int E_DIM = 1024;
constexpr float LOG2E = 1.44269504f;

using gas1 = const __attribute__((address_space(1))) void;
using las3 = __attribute__((address_space(3))) void;

__device__ __forceinline__ void gload_lds16(const bf16* g, bf16* l) {
  __builtin_amdgcn_global_load_lds((gas1*)g, (las3*)l, 16, 0, 0);
}
__device__ __forceinline__ float fexp2(float x) { return __builtin_amdgcn_exp2f(x); }

// ---------------- fp32 -> bf16 bulk convert ----------------------------------------
struct CvtArgs {
  const float* src[7];
  bf16* dst[7];
  int start[8];
};
__global__ __launch_bounds__(256) void cvt_f32_bf16(CvtArgs a)
{
  int blk = blockIdx.x;
  int t = 0;
#pragma unroll
  for (int i = 1; i < 7; ++i) t += (blk >= a.start[i]);
  size_t off = ((size_t)(blk - a.start[t]) * 256 + threadIdx.x) * 8;
  const float* s = a.src[t];
  float4 v0 = *(const float4*)&s[off];
  float4 v1 = *(const float4*)&s[off + 4];
  bf16x8 o;
  o[0] = (bf16)v0.x; o[1] = (bf16)v0.y; o[2] = (bf16)v0.z; o[3] = (bf16)v0.w;
  o[4] = (bf16)v1.x; o[5] = (bf16)v1.y; o[6] = (bf16)v1.z; o[7] = (bf16)v1.w;
  *(bf16x8*)&a.dst[t][off] = o;
}

// ---------------- qkv GEMM: BK=64; grid (m=32, n=8, z=3); V -> Vt via LDS ----------
struct GemmBatch {
  const bf16* A[3];
  const bf16* W[3];
  const float* bias[3];
  bf16* C[3];
  float scale[3];
  int transpose[3];
};
__global__ __launch_bounds__(256) void gemm_qkv(GemmBatch gb)
{
  constexpr int K = 1024, N = 1024;
  const int z = blockIdx.z;
  const bf16* __restrict__ A = gb.A[z];
  const bf16* __restrict__ W = gb.W[z];
  const float* __restrict__ bias = gb.bias[z];
  bf16* __restrict__ C = gb.C[z];
  const float scale = gb.scale[z];

  __shared__ bf16 sm[2 * 128 * 64];   // As | Bs ; reused as V^T transpose buffer
  bf16* const As = sm;
  bf16* const Bs = sm + 128 * 64;

  const int tid = threadIdx.x, wave = tid >> 6, lane = tid & 63;
  const int c = lane & 15, q = lane >> 4;
  const int m0 = blockIdx.x * 128, n0 = blockIdx.y * 128;  // m on x: XCD-local A slab
  const int wr = wave >> 1, wc = wave & 1;
  const int ksub = lane >> 3;
  const int kperm = ((lane & 7) ^ ksub) * 8;
  const int kx = 8 * (c & 7);

  f32x4 acc[4][4] = {};

  for (int kb = 0; kb < K; kb += 64) {
    __syncthreads();
#pragma unroll
    for (int i = 0; i < 4; ++i) {
      int row = wave * 32 + i * 8 + ksub;
      gload_lds16(&A[(size_t)(m0 + row) * K + kb + kperm], &As[(wave * 32 + i * 8) * 64]);
      gload_lds16(&W[(size_t)(n0 + row) * K + kb + kperm], &Bs[(wave * 32 + i * 8) * 64]);
    }
    __syncthreads();

#pragma unroll
    for (int kk = 0; kk < 2; ++kk) {
      bf16x8 af[4], bf[4];
#pragma unroll
      for (int mf = 0; mf < 4; ++mf)
        af[mf] = *(const bf16x8*)&As[(wr * 64 + mf * 16 + c) * 64 + ((kk * 32 + q * 8) ^ kx)];
#pragma unroll
      for (int nf = 0; nf < 4; ++nf)
        bf[nf] = *(const bf16x8*)&Bs[(wc * 64 + nf * 16 + c) * 64 + ((kk * 32 + q * 8) ^ kx)];
#pragma unroll
      for (int mf = 0; mf < 4; ++mf)
#pragma unroll
        for (int nf = 0; nf < 4; ++nf)
          acc[mf][nf] = __builtin_amdgcn_mfma_f32_16x16x32_bf16(af[mf], bf[nf], acc[mf][nf], 0, 0, 0);
    }
  }

  if (gb.transpose[z]) {
    __syncthreads();
    bf16* Tv = sm;
#pragma unroll
    for (int nf = 0; nf < 4; ++nf) {
      int colL = wc * 64 + nf * 16 + c;
      float bv = bias[n0 + colL];
      int xw = 2 * (colL & 15);
#pragma unroll
      for (int mf = 0; mf < 4; ++mf) {
        int chunk4 = wr * 16 + mf * 4 + q;
        bf16x4 pk;
#pragma unroll
        for (int r = 0; r < 4; ++r) pk[r] = (bf16)(acc[mf][nf][r] + bv);
        *(bf16x4*)&Tv[colL * 128 + ((chunk4 ^ xw) << 2)] = pk;
      }
    }
    __syncthreads();
    const int bb = m0 >> 11, tbase = m0 & 2047;
#pragma unroll
    for (int p = 0; p < 8; ++p) {
      int colL = p * 16 + (tid >> 4);
      int j = tid & 15;
      bf16x8 v = *(const bf16x8*)&Tv[colL * 128 + (((2 * j) ^ (2 * (colL & 15))) << 2)];
      int colg = n0 + colL;
      int hh = colg >> 6, d = colg & 63;
      *(bf16x8*)&C[(((size_t)bb * NH + hh) * 64 + d) * 2048 + tbase + j * 8] = v;
    }
  } else {
#pragma unroll
    for (int nf = 0; nf < 4; ++nf) {
      int col = n0 + wc * 64 + nf * 16 + c;
      float bv = bias[col];
#pragma unroll
      for (int mf = 0; mf < 4; ++mf)
#pragma unroll
        for (int r = 0; r < 4; ++r) {
          int row = m0 + wr * 64 + mf * 16 + q * 4 + r;
          C[(size_t)row * N + col] = (bf16)((acc[mf][nf][r] + bv) * scale);
        }
    }
  }
}

// ---------------- out projection: 128x64 tiles, BK=64; grid (m=32, n=16) -----------
__global__ __launch_bounds__(256) void gemm_out(
    const bf16* __restrict__ A, const bf16* __restrict__ W,
    const float* __restrict__ bias, float* __restrict__ C)
{
  constexpr int K = 1024, N = 1024;
  __shared__ bf16 As[128 * 64];
  __shared__ bf16 Bs[64 * 64];
  const int tid = threadIdx.x, wave = tid >> 6, lane = tid & 63;
  const int c = lane & 15, q = lane >> 4;
  const int m0 = blockIdx.x * 128, n0 = blockIdx.y * 64;   // m on x: XCD-local A slab
  const int wr = wave >> 1, wc = wave & 1;
  const int ksub = lane >> 3;
  const int kperm = ((lane & 7) ^ ksub) * 8;
  const int kx = 8 * (c & 7);

  f32x4 acc[4][2] = {};

  for (int kb = 0; kb < K; kb += 64) {
    __syncthreads();
#pragma unroll
    for (int i = 0; i < 4; ++i) {
      int row = wave * 32 + i * 8 + ksub;
      gload_lds16(&A[(size_t)(m0 + row) * K + kb + kperm], &As[(wave * 32 + i * 8) * 64]);
    }
#pragma unroll
    for (int i = 0; i < 2; ++i) {
      int row = wave * 16 + i * 8 + ksub;
      gload_lds16(&W[(size_t)(n0 + row) * K + kb + kperm], &Bs[(wave * 16 + i * 8) * 64]);
    }
    __syncthreads();

#pragma unroll
    for (int kk = 0; kk < 2; ++kk) {
      bf16x8 af[4], bf[2];
#pragma unroll
      for (int mf = 0; mf < 4; ++mf)
        af[mf] = *(const bf16x8*)&As[(wr * 64 + mf * 16 + c) * 64 + ((kk * 32 + q * 8) ^ kx)];
#pragma unroll
      for (int nf = 0; nf < 2; ++nf)
        bf[nf] = *(const bf16x8*)&Bs[(wc * 32 + nf * 16 + c) * 64 + ((kk * 32 + q * 8) ^ kx)];
#pragma unroll
      for (int mf = 0; mf < 4; ++mf)
#pragma unroll
        for (int nf = 0; nf < 2; ++nf)
          acc[mf][nf] = __builtin_amdgcn_mfma_f32_16x16x32_bf16(af[mf], bf[nf], acc[mf][nf], 0, 0, 0);
    }
  }

#pragma unroll
  for (int nf = 0; nf < 2; ++nf) {
    int col = n0 + wc * 32 + nf * 16 + c;
    float bv = bias[col];
#pragma unroll
    for (int mf = 0; mf < 4; ++mf)
#pragma unroll
      for (int r = 0; r < 4; ++r) {
        int row = m0 + wr * 64 + mf * 16 + q * 4 + r;
        C[(size_t)row * N + col] = acc[mf][nf][r] + bv;
      }
  }
}

// ---------------- Flash, S^T form, s-stage 128, exp2 softmax -----------------------
// grid (H=16, T/128=16, B); blockIdx.x = h -> all t-blocks of a head on one XCD.
__global__ __launch_bounds__(256, 2) void flash_ctx(
    const bf16* __restrict__ Qp, const bf16* __restrict__ Kp, const bf16* __restrict__ Vt,
    bf16* __restrict__ ctx, float* __restrict__ cOut)
{
  __shared__ bf16 Ks[128 * 64];       // [s][k], chunk ^ (s&7)
  __shared__ bf16 Vts[64 * 128];      // [d][s], chunk swizzled
  __shared__ bf16 Ps[4][32 * 68];     // per-wave P [t-local][64s sub-tile], pad 68

  const int tid = threadIdx.x, wave = tid >> 6, lane = tid & 63;
  const int c = lane & 15, q = lane >> 4;
  const int b = blockIdx.z, h = blockIdx.x, t0 = blockIdx.y * 128;
  const size_t baseQ = (size_t)b * Tq * E_DIM + h * 64;
  const size_t baseK = (size_t)b * Sk * E_DIM + h * 64;
  const size_t baseV = ((size_t)b * NH + h) * 64 * 2048;
  const int tw[2] = { t0 + wave * 32 + c, t0 + wave * 32 + c + 16 };

  bf16x8 qf[2][2];
#pragma unroll
  for (int tf = 0; tf < 2; ++tf)
#pragma unroll
    for (int kk = 0; kk < 2; ++kk)
      qf[tf][kk] = *(const bf16x8*)&Qp[baseQ + (size_t)tw[tf] * E_DIM + kk * 32 + q * 8];

  f32x4 o_acc[2][4] = {};
  float m2[2] = {-3e38f, -3e38f}, l_st[2] = {0.f, 0.f};

  const int ksub = lane >> 3;
  const int kperm = ((lane & 7) ^ ksub) * 8;
  const int vsub = lane >> 4;
  const int kx = 8 * (c & 7);

  for (int s0 = 0; s0 < Sk; s0 += 128) {
    __syncthreads();
#pragma unroll
    for (int i = 0; i < 4; ++i) {
      int srow = wave * 32 + i * 8 + ksub;
      gload_lds16(&Kp[baseK + (size_t)(s0 + srow) * E_DIM + kperm], &Ks[(wave * 32 + i * 8) * 64]);
      int drow = wave * 16 + i * 4 + vsub;
      int vsw = (4 * (i & 1) + vsub);
      gload_lds16(&Vt[baseV + (size_t)drow * 2048 + s0 + (((lane & 15) ^ vsw) * 8)],
                  &Vts[(wave * 16 + i * 4) * 128]);
    }
    __syncthreads();

    // S^T[128s][32t]
    f32x4 sa[2][8] = {};
#pragma unroll
    for (int kk = 0; kk < 2; ++kk) {
#pragma unroll
      for (int mf = 0; mf < 8; ++mf) {
        bf16x8 af = *(const bf16x8*)&Ks[(mf * 16 + c) * 64 + ((kk * 32 + q * 8) ^ kx)];
#pragma unroll
        for (int tf = 0; tf < 2; ++tf)
          sa[tf][mf] = __builtin_amdgcn_mfma_f32_16x16x32_bf16(af, qf[tf][kk], sa[tf][mf], 0, 0, 0);
      }
    }

    // online softmax over full 128-s stage
    float mn2[2], psum[2] = {0.f, 0.f};
#pragma unroll
    for (int tf = 0; tf < 2; ++tf) {
      float tm = -3e38f;
#pragma unroll
      for (int mf = 0; mf < 8; ++mf)
        tm = fmaxf(tm, fmaxf(fmaxf(sa[tf][mf][0], sa[tf][mf][1]),
                             fmaxf(sa[tf][mf][2], sa[tf][mf][3])));
      tm = fmaxf(tm, __shfl_xor(tm, 16));
      tm = fmaxf(tm, __shfl_xor(tm, 32));
      mn2[tf] = fmaxf(m2[tf], tm * LOG2E);
      float alpha = fexp2(m2[tf] - mn2[tf]);
      m2[tf] = mn2[tf];
      l_st[tf] *= alpha;
#pragma unroll
      for (int mf = 0; mf < 4; ++mf)
#pragma unroll
        for (int r = 0; r < 4; ++r) o_acc[tf][mf][r] *= alpha;
    }

    // two 64-s sub-steps: exp2 -> per-wave P -> PV
#pragma unroll
    for (int sub = 0; sub < 2; ++sub) {
#pragma unroll
      for (int tf = 0; tf < 2; ++tf)
#pragma unroll
        for (int mf = 0; mf < 4; ++mf) {
          bf16x4 pb;
#pragma unroll
          for (int r = 0; r < 4; ++r) {
            float p = fexp2(__builtin_fmaf(sa[tf][sub * 4 + mf][r], LOG2E, -mn2[tf]));
            psum[tf] += p;
            pb[r] = (bf16)p;
          }
          *(bf16x4*)&Ps[wave][(c + 16 * tf) * 68 + mf * 16 + q * 4] = pb;
        }
#pragma unroll
      for (int kk2 = 0; kk2 < 2; ++kk2) {
        bf16x8 af[4], bfr[2];
#pragma unroll
        for (int mf2 = 0; mf2 < 4; ++mf2)
          af[mf2] = *(const bf16x8*)&Vts[(mf2 * 16 + c) * 128 +
                                         ((sub * 64 + kk2 * 32 + q * 8) ^ kx)];
#pragma unroll
        for (int tf = 0; tf < 2; ++tf)
          bfr[tf] = *(const bf16x8*)&Ps[wave][(c + 16 * tf) * 68 + kk2 * 32 + q * 8];
#pragma unroll
        for (int tf = 0; tf < 2; ++tf)
#pragma unroll
          for (int mf2 = 0; mf2 < 4; ++mf2)
            o_acc[tf][mf2] = __builtin_amdgcn_mfma_f32_16x16x32_bf16(af[mf2], bfr[tf], o_acc[tf][mf2], 0, 0, 0);
      }
    }

#pragma unroll
    for (int tf = 0; tf < 2; ++tf) {
      float ps = psum[tf];
      ps += __shfl_xor(ps, 16);
      ps += __shfl_xor(ps, 32);
      l_st[tf] += ps;
    }
  }

  // epilogue: ctx = O/l; c = m2 + log2(l) for attn_max
#pragma unroll
  for (int tf = 0; tf < 2; ++tf) {
    float inv = 1.f / l_st[tf];
#pragma unroll
    for (int mf2 = 0; mf2 < 4; ++mf2) {
      bf16x4 ov;
#pragma unroll
      for (int r = 0; r < 4; ++r) ov[r] = (bf16)(o_acc[tf][mf2][r] * inv);
      *(bf16x4*)&ctx[baseQ + (size_t)tw[tf] * E_DIM + mf2 * 16 + q * 4] = ov;
    }
    if (q == 0)
      cOut[((size_t)b * NH + h) * Tq + tw[tf]] = m2[tf] + __log2f(l_st[tf]);
  }
}

// ---------------- attn_max: double-buffered K DMA, 1 barrier/head ------------------
// grid (S/128=16, T/128=16, B); id mod 8 = s-block -> K sharers XCD-local.
__global__ __launch_bounds__(256) void attn_max_k(
    const bf16* __restrict__ Qp, const bf16* __restrict__ Kp,
    const float* __restrict__ cArr, float* __restrict__ amax)
{
  __shared__ bf16 Ks[2][128 * 64];
  const int tid = threadIdx.x, wave = tid >> 6, lane = tid & 63;
  const int c = lane & 15, q = lane >> 4;
  const int b = blockIdx.z, t0 = blockIdx.y * 128, s0 = blockIdx.x * 128;
  const int tw[2] = { t0 + wave * 32 + c, t0 + wave * 32 + c + 16 };
  const int ksub = lane >> 3;
  const int kperm = ((lane & 7) ^ ksub) * 8;
  const int kx = 8 * (c & 7);

  f32x4 vmax[2][8] = {};

  // pre-issue head 0 K-tile
  {
    const size_t baseK0 = (size_t)b * Sk * E_DIM;
#pragma unroll
    for (int i = 0; i < 4; ++i) {
      int srow = wave * 32 + i * 8 + ksub;
      gload_lds16(&Kp[baseK0 + (size_t)(s0 + srow) * E_DIM + kperm],
                  &Ks[0][(wave * 32 + i * 8) * 64]);
    }
  }

  for (int h = 0; h < NH; ++h) {
    const int cur = h & 1;
    const size_t baseQ = (size_t)b * Tq * E_DIM + h * 64;
    bf16x8 qf[2][2];
    float ch[2];
#pragma unroll
    for (int tf = 0; tf < 2; ++tf) {
#pragma unroll
      for (int kk = 0; kk < 2; ++kk)
        qf[tf][kk] = *(const bf16x8*)&Qp[baseQ + (size_t)tw[tf] * E_DIM + kk * 32 + q * 8];
      ch[tf] = cArr[((size_t)b * NH + h) * Tq + tw[tf]];
    }
    __syncthreads();   // waits DMA for Ks[cur]; Ks[cur^1] readers finished last iter
    if (h + 1 < NH) {
      const size_t baseK1 = (size_t)b * Sk * E_DIM + (h + 1) * 64;
#pragma unroll
      for (int i = 0; i < 4; ++i) {
        int srow = wave * 32 + i * 8 + ksub;
        gload_lds16(&Kp[baseK1 + (size_t)(s0 + srow) * E_DIM + kperm],
                    &Ks[cur ^ 1][(wave * 32 + i * 8) * 64]);
      }
    }

#pragma unroll
    for (int mf = 0; mf < 8; ++mf) {
      f32x4 sa[2] = {};
#pragma unroll
      for (int kk = 0; kk < 2; ++kk) {
        bf16x8 af = *(const bf16x8*)&Ks[cur][(mf * 16 + c) * 64 + ((kk * 32 + q * 8) ^ kx)];
#pragma unroll
        for (int tf = 0; tf < 2; ++tf)
          sa[tf] = __builtin_amdgcn_mfma_f32_16x16x32_bf16(af, qf[tf][kk], sa[tf], 0, 0, 0);
      }
#pragma unroll
      for (int tf = 0; tf < 2; ++tf)
#pragma unroll
        for (int r = 0; r < 4; ++r) {
          float p = fexp2(__builtin_fmaf(sa[tf][r], LOG2E, -ch[tf]));
          vmax[tf][mf][r] = fmaxf(vmax[tf][mf][r], p);
        }
    }
  }

  // LDS-transposed coalesced stores: Tf[t 128][s-local 32] fp32, 4 passes
  __syncthreads();
  float* Tf = (float*)Ks;
#pragma unroll
  for (int pp = 0; pp < 4; ++pp) {
#pragma unroll
    for (int tf = 0; tf < 2; ++tf) {
      int tl = wave * 32 + 16 * tf + c;
#pragma unroll
      for (int ml = 0; ml < 2; ++ml) {
        int chunk4 = ml * 4 + q;
        *(f32x4*)&Tf[tl * 32 + ((chunk4 ^ (c & 7)) << 2)] = vmax[tf][2 * pp + ml];
      }
    }
    __syncthreads();
#pragma unroll
    for (int it = 0; it < 4; ++it) {
      int trow = it * 32 + (tid >> 3);
      int j = tid & 7;
      f32x4 v = *(const f32x4*)&Tf[trow * 32 + ((j ^ (trow & 7)) << 2)];
      *(f32x4*)&amax[((size_t)b * Tq + t0 + trow) * Sk + s0 + pp * 32 + j * 4] = v;
    }
    __syncthreads();
  }
}

// ---------------- launch -----------------------------------------------------------
extern "C" void kernel_launch(void* const* d_in, const int* in_sizes, int n_in,
                              void* d_out, int out_size, void* d_ws, size_t ws_size,
                              hipStream_t stream)
{
  const float* query = (const float*)d_in[0];
  const float* key_i = (const float*)d_in[1];
  const float* value = (const float*)d_in[2];
  const float* Wq = (const float*)d_in[5];
  const float* bq = (const float*)d_in[6];
  const float* Wk = (const float*)d_in[7];
  const float* bk = (const float*)d_in[8];
  const float* Wv = (const float*)d_in[9];
  const float* bv = (const float*)d_in[10];
  const float* Wo = (const float*)d_in[11];
  const float* bo = (const float*)d_in[12];

  float* outp = (float*)d_out;
  float* amax = outp + (size_t)Bsz * Tq * E_DIM;

  char* ws = (char*)d_ws;
  bf16* Xq  = (bf16*)(ws);
  bf16* Xk  = (bf16*)(ws + 8388608);
  bf16* Xv  = (bf16*)(ws + 16777216);
  bf16* Wqb = (bf16*)(ws + 25165824);
  bf16* Wkb = (bf16*)(ws + 27262976);
  bf16* Wvb = (bf16*)(ws + 29360128);
  bf16* Wob = (bf16*)(ws + 31457280);
  bf16* Qp  = (bf16*)(ws + 33554432);
  bf16* Kp  = (bf16*)(ws + 41943040);
  bf16* Vt  = (bf16*)(ws + 50331648);
  bf16* ctx = Xq;  // Xq dead after qkv GEMM
  float* cA = (float*)(ws + 58720256);

  CvtArgs ca;
  ca.src[0] = query; ca.dst[0] = Xq;
  ca.src[1] = key_i; ca.dst[1] = Xk;
  ca.src[2] = value; ca.dst[2] = Xv;
  ca.src[3] = Wq;    ca.dst[3] = Wqb;
  ca.src[4] = Wk;    ca.dst[4] = Wkb;
  ca.src[5] = Wv;    ca.dst[5] = Wvb;
  ca.src[6] = Wo;    ca.dst[6] = Wob;
  ca.start[0] = 0;    ca.start[1] = 2048; ca.start[2] = 4096; ca.start[3] = 6144;
  ca.start[4] = 6656; ca.start[5] = 7168; ca.start[6] = 7680; ca.start[7] = 8192;
  cvt_f32_bf16<<<8192, 256, 0, stream>>>(ca);

  GemmBatch g1;
  g1.A[0] = Xq; g1.A[1] = Xk; g1.A[2] = Xv;
  g1.W[0] = Wqb; g1.W[1] = Wkb; g1.W[2] = Wvb;
  g1.bias[0] = bq; g1.bias[1] = bk; g1.bias[2] = bv;
  g1.C[0] = Qp; g1.C[1] = Kp; g1.C[2] = Vt;
  g1.scale[0] = 0.125f; g1.scale[1] = 1.f; g1.scale[2] = 1.f;
  g1.transpose[0] = 0; g1.transpose[1] = 0; g1.transpose[2] = 1;
  gemm_qkv<<<dim3(32, 8, 3), 256, 0, stream>>>(g1);

  flash_ctx<<<dim3(16, 16, 2), 256, 0, stream>>>(Qp, Kp, Vt, ctx, cA);
  attn_max_k<<<dim3(16, 16, 2), 256, 0, stream>>>(Qp, Kp, cA, amax);
  gemm_out<<<dim3(32, 16), 256, 0, stream>>>(ctx, Wob, bo, outp);
}